// Round 16
// baseline (426.886 us; speedup 1.0000x reference)
//
#include <hip/hip_runtime.h>

#define NN    50000
#define ERAW  800000
#define ETOT  850000
#define NBUCK 782            // ceil(NN/64) buckets of 64 dst nodes
#define EBR   1280           // fixed edges-per-bucket region (mean 1087, sigma 33)
#define EPB_A 4096
#define NBLK_A ((ETOT + EPB_A - 1) / EPB_A)   // 208
#define NCNT  (NBUCK * 64)
#define INV_LN2 1.4426950408889634f

typedef __attribute__((ext_vector_type(8))) short bf16x8;
typedef __attribute__((ext_vector_type(4))) float f32x4;

union U16x8 { uint4 u; bf16x8 s; };
__device__ __forceinline__ bf16x8 as_bf(uint4 v) { U16x8 t; t.u = v; return t.s; }

__device__ __forceinline__ void edge_sd(const int* __restrict__ ei, int e, int& s, int& d) {
    if (e < ERAW) { s = ei[e]; d = ei[ERAW + e]; }
    else { int n = e - ERAW; s = n; d = n; }
}

__device__ __forceinline__ unsigned pack_bf16x2(float a, float b) {
    unsigned ua = __float_as_uint(a), ub = __float_as_uint(b);
    ua += 0x7fffu + ((ua >> 16) & 1u);
    ub += 0x7fffu + ((ub >> 16) & 1u);
    return (ua >> 16) | (ub & 0xffff0000u);
}
__device__ __forceinline__ float2 unpack_bf16x2(unsigned v) {
    float2 r;
    r.x = __uint_as_float(v << 16);
    r.y = __uint_as_float(v & 0xffff0000u);
    return r;
}

// ---------------- prep (blocks 0..45) + x->bf16 conversion (blocks 46..) ----------------
__global__ void prep_conv(const float* __restrict__ x,
                          const float* __restrict__ W0, const float* __restrict__ W1,
                          const float* __restrict__ W2,
                          const float* __restrict__ as0, const float* __restrict__ ad0,
                          const float* __restrict__ as1, const float* __restrict__ ad1,
                          const float* __restrict__ as2, const float* __restrict__ ad2,
                          unsigned* __restrict__ Wbp0, unsigned* __restrict__ Wbp1,
                          unsigned* __restrict__ Wadp0, unsigned* __restrict__ Wadp1,
                          float* __restrict__ W2e, int* __restrict__ cursor,
                          int* __restrict__ gbins, unsigned* __restrict__ xb) {
    if (blockIdx.x >= 46) {
        int g = (blockIdx.x - 46) * 256 + threadIdx.x;
        if (g >= NN * 32) return;
        float4 v = ((const float4*)x)[g];
        uint2 o;
        o.x = pack_bf16x2(v.x, v.y);
        o.y = pack_bf16x2(v.z, v.w);
        ((uint2*)xb)[g] = o;
        return;
    }
    int g = blockIdx.x * 256 + threadIdx.x;
    if (g < 4096) {
        // B-fragment prepack of W0/W1: col = ct*16+(l&15), k = kc*32+(l>>4)*8 ..+7
        int which = g >> 11;
        int r = g & 2047;
        int ct = r >> 8, kc = (r >> 6) & 3, l = r & 63;
        int lr = l & 15, lg = l >> 4;
        int col = ct * 16 + lr, k0 = kc * 32 + lg * 8;
        const float* W = which ? W1 : W0;
        unsigned* O = which ? Wbp1 : Wbp0;
        uint4 o;
        o.x = pack_bf16x2(W[(k0 + 0) * 128 + col], W[(k0 + 1) * 128 + col]);
        o.y = pack_bf16x2(W[(k0 + 2) * 128 + col], W[(k0 + 3) * 128 + col]);
        o.z = pack_bf16x2(W[(k0 + 4) * 128 + col], W[(k0 + 5) * 128 + col]);
        o.w = pack_bf16x2(W[(k0 + 6) * 128 + col], W[(k0 + 7) * 128 + col]);
        ((uint4*)O)[(ct * 4 + kc) * 64 + l] = o;
    } else if (g < 4608) {
        // Folded attention weights scaled by 1/ln2 (exp2 trick)
        int gg = g - 4096;
        int which = gg >> 8;
        int r = gg & 255;
        int kc = r >> 6, l = r & 63;
        int lr = l & 15, lg = l >> 4;
        const float* W = which ? W1 : W0;
        const float* av = (lr < 8) ? (which ? as1 : as0) : (which ? ad1 : ad0);
        unsigned* O = which ? Wadp1 : Wadp0;
        int h = lr & 7;
        int k0 = kc * 32 + lg * 8;
        float v[8];
        #pragma unroll
        for (int j = 0; j < 8; ++j) {
            float s = 0.f;
            #pragma unroll
            for (int c = 0; c < 16; ++c) s += W[(k0 + j) * 128 + h * 16 + c] * av[h * 16 + c];
            v[j] = s * INV_LN2;
        }
        uint4 o;
        o.x = pack_bf16x2(v[0], v[1]);
        o.y = pack_bf16x2(v[2], v[3]);
        o.z = pack_bf16x2(v[4], v[5]);
        o.w = pack_bf16x2(v[6], v[7]);
        ((uint4*)O)[kc * 64 + l] = o;
    } else if (g < 4608 + 6144) {
        // W2e[128][48]: cols 0..39 = W2, col 40 = W2@as2/ln2, col 41 = W2@ad2/ln2
        int gg = g - 4608;
        int k = gg / 48, j = gg - k * 48;
        float v = 0.f;
        if (j < 40) v = W2[k * 40 + j];
        else if (j == 40) { for (int c = 0; c < 40; ++c) v += W2[k * 40 + c] * as2[c]; v *= INV_LN2; }
        else if (j == 41) { for (int c = 0; c < 40; ++c) v += W2[k * 40 + c] * ad2[c]; v *= INV_LN2; }
        W2e[k * 48 + j] = v;
    } else if (g < 10752 + NBUCK) {
        int b = g - 10752;
        cursor[b] = b * EBR;
    } else if (g < 10752 + NBUCK + 64) {
        gbins[g - 10752 - NBUCK] = 0;
    }
}

// ---------------- CSR: bucket scatter into fixed regions ----------------
__global__ __launch_bounds__(256) void kA3(const int* __restrict__ ei, int* __restrict__ cursor,
                                           unsigned* __restrict__ ebkt) {
    __shared__ int lb[NBUCK];
    int t = threadIdx.x;
    for (int i = t; i < NBUCK; i += 256) lb[i] = 0;
    __syncthreads();
    int base = blockIdx.x * EPB_A;
    #pragma unroll 4
    for (int k = 0; k < EPB_A / 256; ++k) {
        int e = base + k * 256 + t;
        if (e < ETOT) {
            int s, d; edge_sd(ei, e, s, d); (void)s;
            atomicAdd(&lb[d >> 6], 1);
        }
    }
    __syncthreads();
    for (int i = t; i < NBUCK; i += 256) {
        int c = lb[i];
        lb[i] = c ? atomicAdd(&cursor[i], c) : 0;
    }
    __syncthreads();
    #pragma unroll 4
    for (int k = 0; k < EPB_A / 256; ++k) {
        int e = base + k * 256 + t;
        if (e < ETOT) {
            int s, d; edge_sd(ei, e, s, d);
            int b = d >> 6;
            int pos = atomicAdd(&lb[b], 1);
            if (pos < (b + 1) * EBR)                      // overflow clamp (P ~ 1e-6)
                ebkt[pos] = ((unsigned)d << 16) | (unsigned)s;
        }
    }
}

// per-bucket count + scan + row_start/row_end + degree histogram + within-region scatter
__global__ __launch_bounds__(256) void kB(const int* __restrict__ cursor,
                                          const unsigned* __restrict__ ebkt,
                                          int* __restrict__ row_start, int* __restrict__ row_end,
                                          int* __restrict__ gbins,
                                          unsigned short* __restrict__ src_u16) {
    __shared__ int lc[64];
    int b = blockIdx.x, t = threadIdx.x;
    if (t < 64) lc[t] = 0;
    __syncthreads();
    int s0 = b * EBR;
    int s1 = cursor[b]; if (s1 > s0 + EBR) s1 = s0 + EBR;
    for (int i = s0 + t; i < s1; i += 256) atomicAdd(&lc[(ebkt[i] >> 16) & 63], 1);
    __syncthreads();
    if (t < 64) {
        int v = lc[t];
        int inc = v;
        #pragma unroll
        for (int off = 1; off < 64; off <<= 1) {
            int u = __shfl_up(inc, off);
            if (t >= off) inc += u;
        }
        int st = s0 + inc - v;
        row_start[b * 64 + t] = st;
        row_end[b * 64 + t] = st + v;
        lc[t] = st;
        // degree histogram over REAL nodes only (phantom slots >= NN would create
        // perm holes + OOB scatter — the round-15 crash)
        if (b * 64 + t < NN) atomicAdd(&gbins[v < 63 ? v : 63], 1);
    }
    __syncthreads();
    for (int i = s0 + t; i < s1; i += 256) {
        unsigned k = ebkt[i];
        int pos = atomicAdd(&lc[(k >> 16) & 63], 1);
        src_u16[pos] = (unsigned short)(k & 0xffffu);
    }
}

// exclusive scan of 64 degree bins -> bin cursors
__global__ void k_degscan(const int* __restrict__ gbins, int* __restrict__ gcur) {
    int t = threadIdx.x;
    int v = gbins[t];
    int inc = v;
    #pragma unroll
    for (int off = 1; off < 64; off <<= 1) {
        int u = __shfl_up(inc, off);
        if (t >= off) inc += u;
    }
    gcur[t] = inc - v;
}

// scatter nodes into degree-sorted permutation (total = NN exactly, no holes)
__global__ void k_degscatter(const int* __restrict__ row_start, const int* __restrict__ row_end,
                             int* __restrict__ gcur, int* __restrict__ perm) {
    int n = blockIdx.x * 256 + threadIdx.x;
    if (n >= NN) return;
    int deg = row_end[n] - row_start[n];
    if (deg > 63) deg = 63;
    int pos = atomicAdd(&gcur[deg], 1);
    perm[pos] = n;
}

// ---------------- MFMA GEMM (layers 0/1) + fused als/ald MFMA ----------------
__global__ __launch_bounds__(256) void gemm_mfma128(
    const uint4* __restrict__ xb, const uint4* __restrict__ Wbp,
    const uint4* __restrict__ Wadp, unsigned* __restrict__ hb,
    float* __restrict__ als, float* __restrict__ ald)
{
    int t = threadIdx.x;
    int wv = t >> 6, l = t & 63;
    int lr = l & 15, lg = l >> 4;
    int n0 = blockIdx.x * 64 + wv * 16;
    int nodeA = n0 + lr; if (nodeA >= NN) nodeA = NN - 1;
    const uint4* xr = xb + (size_t)nodeA * 16;
    uint4 a0 = xr[0 * 4 + lg];
    uint4 a1 = xr[1 * 4 + lg];
    uint4 a2 = xr[2 * 4 + lg];
    uint4 a3 = xr[3 * 4 + lg];
    #pragma unroll
    for (int ct = 0; ct < 8; ++ct) {
        const uint4* bp = Wbp + (size_t)(ct * 4) * 64;
        uint4 b0 = bp[0 * 64 + l];
        uint4 b1 = bp[1 * 64 + l];
        uint4 b2 = bp[2 * 64 + l];
        uint4 b3 = bp[3 * 64 + l];
        f32x4 acc = {0.f, 0.f, 0.f, 0.f};
        acc = __builtin_amdgcn_mfma_f32_16x16x32_bf16(as_bf(a0), as_bf(b0), acc, 0, 0, 0);
        acc = __builtin_amdgcn_mfma_f32_16x16x32_bf16(as_bf(a1), as_bf(b1), acc, 0, 0, 0);
        acc = __builtin_amdgcn_mfma_f32_16x16x32_bf16(as_bf(a2), as_bf(b2), acc, 0, 0, 0);
        acc = __builtin_amdgcn_mfma_f32_16x16x32_bf16(as_bf(a3), as_bf(b3), acc, 0, 0, 0);
        #pragma unroll
        for (int j = 0; j < 4; ++j) {
            float hv = acc[j];
            float nbv = __shfl_xor(hv, 1);
            int node = n0 + lg * 4 + j;
            if ((lr & 1) == 0 && node < NN)
                hb[(size_t)node * 64 + ct * 8 + (lr >> 1)] = pack_bf16x2(hv, nbv);
        }
    }
    // fused attention coefficients (pre-scaled by 1/ln2): cols 0..7 als, 8..15 ald
    {
        uint4 b0 = Wadp[0 * 64 + l];
        uint4 b1 = Wadp[1 * 64 + l];
        uint4 b2 = Wadp[2 * 64 + l];
        uint4 b3 = Wadp[3 * 64 + l];
        f32x4 acc = {0.f, 0.f, 0.f, 0.f};
        acc = __builtin_amdgcn_mfma_f32_16x16x32_bf16(as_bf(a0), as_bf(b0), acc, 0, 0, 0);
        acc = __builtin_amdgcn_mfma_f32_16x16x32_bf16(as_bf(a1), as_bf(b1), acc, 0, 0, 0);
        acc = __builtin_amdgcn_mfma_f32_16x16x32_bf16(as_bf(a2), as_bf(b2), acc, 0, 0, 0);
        acc = __builtin_amdgcn_mfma_f32_16x16x32_bf16(as_bf(a3), as_bf(b3), acc, 0, 0, 0);
        #pragma unroll
        for (int j = 0; j < 4; ++j) {
            int node = n0 + lg * 4 + j;
            if (node < NN) {
                if (lr < 8) als[node * 8 + lr] = acc[j];
                else        ald[node * 8 + (lr - 8)] = acc[j];
            }
        }
    }
}

// ---------------- GEMM layer 2 (bf16 in, W2e with folded als/ald cols) ----------------
__global__ __launch_bounds__(256) void gemm_att40(
    const unsigned* __restrict__ fb, const float* __restrict__ W2e,
    unsigned* __restrict__ hb40, float* __restrict__ als, float* __restrict__ ald)
{
    __shared__ float ws[128 * 48];
    __shared__ unsigned xs[16 * 64];
    int t = threadIdx.x;
    int n0 = blockIdx.x * 16;
    #pragma unroll
    for (int i = 0; i < 6; ++i) ((float4*)ws)[i * 256 + t] = ((const float4*)W2e)[i * 256 + t];
    ((uint4*)xs)[t] = ((const uint4*)fb)[(size_t)n0 * 16 + t];
    __syncthreads();
    int w = t >> 6, c = t & 63;
    int cc = c < 42 ? c : 41;
    float acc[4] = {0.f, 0.f, 0.f, 0.f};
    #pragma unroll 4
    for (int kc = 0; kc < 32; ++kc) {
        float w0 = ws[(kc * 4 + 0) * 48 + cc];
        float w1 = ws[(kc * 4 + 1) * 48 + cc];
        float w2 = ws[(kc * 4 + 2) * 48 + cc];
        float w3 = ws[(kc * 4 + 3) * 48 + cc];
        #pragma unroll
        for (int i = 0; i < 4; ++i) {
            float2 f0 = unpack_bf16x2(xs[(4 * w + i) * 64 + kc * 2]);
            float2 f1 = unpack_bf16x2(xs[(4 * w + i) * 64 + kc * 2 + 1]);
            acc[i] = fmaf(f0.x, w0, acc[i]);
            acc[i] = fmaf(f0.y, w1, acc[i]);
            acc[i] = fmaf(f1.x, w2, acc[i]);
            acc[i] = fmaf(f1.y, w3, acc[i]);
        }
    }
    #pragma unroll
    for (int i = 0; i < 4; ++i) {
        int n = n0 + 4 * w + i;
        float nb = __shfl_xor(acc[i], 1);
        if ((c & 1) == 0 && c < 40) hb40[(size_t)n * 32 + (c >> 1)] = pack_bf16x2(acc[i], nb);
        if (c == 40) als[n] = acc[i];
        if (c == 41) ald[n] = acc[i];
    }
}

// ---------------- fused single-pass softmax + aggregate + finalize ----------------
// FOUR (degree-matched) nodes per wave via perm[]; 16 lanes/node; lane l = one uint4.
template<bool RELU>
__global__ void dst_agg128(const int* __restrict__ perm,
                           const int* __restrict__ row_start, const int* __restrict__ row_end,
                           const unsigned short* __restrict__ src_u16,
                           const float* __restrict__ als, const float* __restrict__ ald,
                           const unsigned* __restrict__ hb, const float* __restrict__ bias,
                           unsigned* __restrict__ outb)
{
    int wp = (blockIdx.x * blockDim.x + threadIdx.x) >> 6;
    if (wp >= NN / 4) return;
    int lane = threadIdx.x & 63;
    int q = lane >> 4, l = lane & 15;
    int node = perm[4 * wp + q];
    int myh = l >> 1;
    float aldv = ald[node * 8 + myh];
    int i = row_start[node], end = row_end[node];
    float4 accA = make_float4(0.f, 0.f, 0.f, 0.f);
    float4 accB = make_float4(0.f, 0.f, 0.f, 0.f);
    float den = 0.f;
    while (__any(i + 4 <= end)) {
        if (i + 4 <= end) {
            int s0 = src_u16[i], s1 = src_u16[i + 1], s2 = src_u16[i + 2], s3 = src_u16[i + 3];
            float e0 = als[s0 * 8 + myh] + aldv;
            float e1 = als[s1 * 8 + myh] + aldv;
            float e2 = als[s2 * 8 + myh] + aldv;
            float e3 = als[s3 * 8 + myh] + aldv;
            uint4 p0 = ((const uint4*)(hb + (size_t)s0 * 64))[l];
            uint4 p1 = ((const uint4*)(hb + (size_t)s1 * 64))[l];
            uint4 p2 = ((const uint4*)(hb + (size_t)s2 * 64))[l];
            uint4 p3 = ((const uint4*)(hb + (size_t)s3 * 64))[l];
            e0 = e0 > 0.f ? e0 : 0.2f * e0;
            e1 = e1 > 0.f ? e1 : 0.2f * e1;
            e2 = e2 > 0.f ? e2 : 0.2f * e2;
            e3 = e3 > 0.f ? e3 : 0.2f * e3;
            float a0 = exp2f(e0), a1 = exp2f(e1), a2 = exp2f(e2), a3 = exp2f(e3);
            den += (a0 + a1) + (a2 + a3);
            float2 t0, t1;
            t0 = unpack_bf16x2(p0.x); t1 = unpack_bf16x2(p0.y);
            accA.x = fmaf(t0.x, a0, accA.x); accA.y = fmaf(t0.y, a0, accA.y);
            accA.z = fmaf(t1.x, a0, accA.z); accA.w = fmaf(t1.y, a0, accA.w);
            t0 = unpack_bf16x2(p0.z); t1 = unpack_bf16x2(p0.w);
            accB.x = fmaf(t0.x, a0, accB.x); accB.y = fmaf(t0.y, a0, accB.y);
            accB.z = fmaf(t1.x, a0, accB.z); accB.w = fmaf(t1.y, a0, accB.w);
            t0 = unpack_bf16x2(p1.x); t1 = unpack_bf16x2(p1.y);
            accA.x = fmaf(t0.x, a1, accA.x); accA.y = fmaf(t0.y, a1, accA.y);
            accA.z = fmaf(t1.x, a1, accA.z); accA.w = fmaf(t1.y, a1, accA.w);
            t0 = unpack_bf16x2(p1.z); t1 = unpack_bf16x2(p1.w);
            accB.x = fmaf(t0.x, a1, accB.x); accB.y = fmaf(t0.y, a1, accB.y);
            accB.z = fmaf(t1.x, a1, accB.z); accB.w = fmaf(t1.y, a1, accB.w);
            t0 = unpack_bf16x2(p2.x); t1 = unpack_bf16x2(p2.y);
            accA.x = fmaf(t0.x, a2, accA.x); accA.y = fmaf(t0.y, a2, accA.y);
            accA.z = fmaf(t1.x, a2, accA.z); accA.w = fmaf(t1.y, a2, accA.w);
            t0 = unpack_bf16x2(p2.z); t1 = unpack_bf16x2(p2.w);
            accB.x = fmaf(t0.x, a2, accB.x); accB.y = fmaf(t0.y, a2, accB.y);
            accB.z = fmaf(t1.x, a2, accB.z); accB.w = fmaf(t1.y, a2, accB.w);
            t0 = unpack_bf16x2(p3.x); t1 = unpack_bf16x2(p3.y);
            accA.x = fmaf(t0.x, a3, accA.x); accA.y = fmaf(t0.y, a3, accA.y);
            accA.z = fmaf(t1.x, a3, accA.z); accA.w = fmaf(t1.y, a3, accA.w);
            t0 = unpack_bf16x2(p3.z); t1 = unpack_bf16x2(p3.w);
            accB.x = fmaf(t0.x, a3, accB.x); accB.y = fmaf(t0.y, a3, accB.y);
            accB.z = fmaf(t1.x, a3, accB.z); accB.w = fmaf(t1.y, a3, accB.w);
            i += 4;
        }
    }
    while (__any(i < end)) {
        if (i < end) {
            int s0 = src_u16[i];
            float e0 = als[s0 * 8 + myh] + aldv;
            e0 = e0 > 0.f ? e0 : 0.2f * e0;
            float a0 = exp2f(e0);
            den += a0;
            uint4 p0 = ((const uint4*)(hb + (size_t)s0 * 64))[l];
            float2 t0 = unpack_bf16x2(p0.x), t1 = unpack_bf16x2(p0.y);
            accA.x = fmaf(t0.x, a0, accA.x); accA.y = fmaf(t0.y, a0, accA.y);
            accA.z = fmaf(t1.x, a0, accA.z); accA.w = fmaf(t1.y, a0, accA.w);
            t0 = unpack_bf16x2(p0.z); t1 = unpack_bf16x2(p0.w);
            accB.x = fmaf(t0.x, a0, accB.x); accB.y = fmaf(t0.y, a0, accB.y);
            accB.z = fmaf(t1.x, a0, accB.z); accB.w = fmaf(t1.y, a0, accB.w);
            ++i;
        }
    }
    float inv = 1.f / (den + 1e-16f);
    float4 bvA = ((const float4*)bias)[2 * l];
    float4 bvB = ((const float4*)bias)[2 * l + 1];
    float4 oA, oB;
    oA.x = accA.x * inv + bvA.x; oA.y = accA.y * inv + bvA.y;
    oA.z = accA.z * inv + bvA.z; oA.w = accA.w * inv + bvA.w;
    oB.x = accB.x * inv + bvB.x; oB.y = accB.y * inv + bvB.y;
    oB.z = accB.z * inv + bvB.z; oB.w = accB.w * inv + bvB.w;
    if (RELU) {
        oA.x = fmaxf(oA.x, 0.f); oA.y = fmaxf(oA.y, 0.f);
        oA.z = fmaxf(oA.z, 0.f); oA.w = fmaxf(oA.w, 0.f);
        oB.x = fmaxf(oB.x, 0.f); oB.y = fmaxf(oB.y, 0.f);
        oB.z = fmaxf(oB.z, 0.f); oB.w = fmaxf(oB.w, 0.f);
    }
    uint4 ob;
    ob.x = pack_bf16x2(oA.x, oA.y);
    ob.y = pack_bf16x2(oA.z, oA.w);
    ob.z = pack_bf16x2(oB.x, oB.y);
    ob.w = pack_bf16x2(oB.z, oB.w);
    ((uint4*)(outb + (size_t)node * 64))[l] = ob;
}

// H=1, C=40: FOUR degree-matched nodes per wave (16 lanes each; l<10 own uint2 pairs).
__global__ void dst_agg40(const int* __restrict__ perm,
                          const int* __restrict__ row_start, const int* __restrict__ row_end,
                          const unsigned short* __restrict__ src_u16,
                          const float* __restrict__ als, const float* __restrict__ ald,
                          const unsigned* __restrict__ hb40, const float* __restrict__ bias,
                          float* __restrict__ out)
{
    int wp = (blockIdx.x * blockDim.x + threadIdx.x) >> 6;
    if (wp >= NN / 4) return;
    int lane = threadIdx.x & 63;
    int q = lane >> 4, l = lane & 15;
    int node = perm[4 * wp + q];
    float aldv = ald[node];
    int i = row_start[node], end = row_end[node];
    float4 acc = make_float4(0.f, 0.f, 0.f, 0.f);
    float den = 0.f;
    while (__any(i + 4 <= end)) {
        if (i + 4 <= end) {
            int s0 = src_u16[i], s1 = src_u16[i + 1], s2 = src_u16[i + 2], s3 = src_u16[i + 3];
            float e0 = als[s0] + aldv;
            float e1 = als[s1] + aldv;
            float e2 = als[s2] + aldv;
            float e3 = als[s3] + aldv;
            uint2 p0 = ((const uint2*)(hb40 + (size_t)s0 * 32))[l];
            uint2 p1 = ((const uint2*)(hb40 + (size_t)s1 * 32))[l];
            uint2 p2 = ((const uint2*)(hb40 + (size_t)s2 * 32))[l];
            uint2 p3 = ((const uint2*)(hb40 + (size_t)s3 * 32))[l];
            e0 = e0 > 0.f ? e0 : 0.2f * e0;
            e1 = e1 > 0.f ? e1 : 0.2f * e1;
            e2 = e2 > 0.f ? e2 : 0.2f * e2;
            e3 = e3 > 0.f ? e3 : 0.2f * e3;
            float b0 = exp2f(e0), b1 = exp2f(e1), b2 = exp2f(e2), b3 = exp2f(e3);
            den += (b0 + b1) + (b2 + b3);
            float2 u0 = unpack_bf16x2(p0.x), v0 = unpack_bf16x2(p0.y);
            float2 u1 = unpack_bf16x2(p1.x), v1 = unpack_bf16x2(p1.y);
            float2 u2 = unpack_bf16x2(p2.x), v2 = unpack_bf16x2(p2.y);
            float2 u3 = unpack_bf16x2(p3.x), v3 = unpack_bf16x2(p3.y);
            acc.x = fmaf(u0.x, b0, acc.x); acc.y = fmaf(u0.y, b0, acc.y);
            acc.z = fmaf(v0.x, b0, acc.z); acc.w = fmaf(v0.y, b0, acc.w);
            acc.x = fmaf(u1.x, b1, acc.x); acc.y = fmaf(u1.y, b1, acc.y);
            acc.z = fmaf(v1.x, b1, acc.z); acc.w = fmaf(v1.y, b1, acc.w);
            acc.x = fmaf(u2.x, b2, acc.x); acc.y = fmaf(u2.y, b2, acc.y);
            acc.z = fmaf(v2.x, b2, acc.z); acc.w = fmaf(v2.y, b2, acc.w);
            acc.x = fmaf(u3.x, b3, acc.x); acc.y = fmaf(u3.y, b3, acc.y);
            acc.z = fmaf(v3.x, b3, acc.z); acc.w = fmaf(v3.y, b3, acc.w);
            i += 4;
        }
    }
    while (__any(i < end)) {
        if (i < end) {
            int s0 = src_u16[i];
            float e0 = als[s0] + aldv;
            e0 = e0 > 0.f ? e0 : 0.2f * e0;
            float b0 = exp2f(e0);
            den += b0;
            uint2 p0 = ((const uint2*)(hb40 + (size_t)s0 * 32))[l];
            float2 u0 = unpack_bf16x2(p0.x), v0 = unpack_bf16x2(p0.y);
            acc.x = fmaf(u0.x, b0, acc.x); acc.y = fmaf(u0.y, b0, acc.y);
            acc.z = fmaf(v0.x, b0, acc.z); acc.w = fmaf(v0.y, b0, acc.w);
            ++i;
        }
    }
    if (l < 10) {
        float inv = 1.f / (den + 1e-16f);
        float4 bv = ((const float4*)bias)[l];
        float4 o;
        o.x = acc.x * inv + bv.x;
        o.y = acc.y * inv + bv.y;
        o.z = acc.z * inv + bv.z;
        o.w = acc.w * inv + bv.w;
        ((float4*)(out + (size_t)node * 40))[l] = o;
    }
}

extern "C" void kernel_launch(void* const* d_in, const int* in_sizes, int n_in,
                              void* d_out, int out_size, void* d_ws, size_t ws_size,
                              hipStream_t stream) {
    const float* x   = (const float*)d_in[0];
    const int*   ei  = (const int*)d_in[1];
    const float* W0  = (const float*)d_in[2];
    const float* as0 = (const float*)d_in[3];
    const float* ad0 = (const float*)d_in[4];
    const float* b0  = (const float*)d_in[5];
    const float* W1  = (const float*)d_in[6];
    const float* as1 = (const float*)d_in[7];
    const float* ad1 = (const float*)d_in[8];
    const float* b1  = (const float*)d_in[9];
    const float* W2  = (const float*)d_in[10];
    const float* as2 = (const float*)d_in[11];
    const float* ad2 = (const float*)d_in[12];
    const float* b2  = (const float*)d_in[13];
    float* out = (float*)d_out;

    float* ws = (float*)d_ws;
    size_t off = 0;
    unsigned* hb   = (unsigned*)(ws + off); off += (size_t)NN * 64;
    unsigned* xb   = (unsigned*)(ws + off); off += (size_t)NN * 64;
    unsigned* fAb  = (unsigned*)(ws + off); off += (size_t)NN * 64;
    unsigned* fBb  = (unsigned*)(ws + off); off += (size_t)NN * 64;
    unsigned* hb40 = (unsigned*)(ws + off); off += (size_t)NN * 32;
    float* als     = ws + off; off += (size_t)NN * 8;
    float* ald     = ws + off; off += (size_t)NN * 8;
    unsigned* Wbp0 = (unsigned*)(ws + off); off += 8192;
    unsigned* Wbp1 = (unsigned*)(ws + off); off += 8192;
    unsigned* Wadp0 = (unsigned*)(ws + off); off += 1024;
    unsigned* Wadp1 = (unsigned*)(ws + off); off += 1024;
    float* W2e     = ws + off; off += 128 * 48;
    int* ibase      = (int*)(ws + off);
    int* cursor     = ibase; ibase += NBUCK;
    int* row_start  = ibase; ibase += NCNT;
    int* row_end    = ibase; ibase += NCNT;
    int* gbins      = ibase; ibase += 64;
    int* gcur       = ibase; ibase += 64;
    int* perm       = ibase; ibase += NN;
    unsigned* ebkt  = (unsigned*)ibase; ibase += NBUCK * EBR;
    unsigned short* src_u16 = (unsigned short*)ibase;

    const int TB = 256;

    // ---- prep (weights, folded+scaled attention weights, cursor, bins) + x->bf16 ----
    prep_conv<<<46 + (NN * 32 + TB - 1) / TB, TB, 0, stream>>>(
        x, W0, W1, W2, as0, ad0, as1, ad1, as2, ad2,
        Wbp0, Wbp1, Wadp0, Wadp1, W2e, cursor, gbins, xb);
    // ---- CSR build (fixed-region bucket sort; shared by all 3 layers) ----
    kA3<<<NBLK_A, 256, 0, stream>>>(ei, cursor, ebkt);
    kB<<<NBUCK, 256, 0, stream>>>(cursor, ebkt, row_start, row_end, gbins, src_u16);
    // ---- degree-balanced node permutation ----
    k_degscan<<<1, 64, 0, stream>>>(gbins, gcur);
    k_degscatter<<<(NN + TB - 1) / TB, TB, 0, stream>>>(row_start, row_end, gcur, perm);

    const int GGM   = (NN + 63) / 64;                 // 782
    const int GG40  = NN / 16;                        // 3125
    const int GAGG4 = ((NN / 4) * 64 + TB - 1) / TB;  // 3125

    // ---- Layer 0 ----
    gemm_mfma128<<<GGM, 256, 0, stream>>>((const uint4*)xb, (const uint4*)Wbp0,
                                          (const uint4*)Wadp0, hb, als, ald);
    dst_agg128<true><<<GAGG4, TB, 0, stream>>>(perm, row_start, row_end, src_u16, als, ald, hb, b0, fAb);

    // ---- Layer 1 ----
    gemm_mfma128<<<GGM, 256, 0, stream>>>((const uint4*)fAb, (const uint4*)Wbp1,
                                          (const uint4*)Wadp1, hb, als, ald);
    dst_agg128<true><<<GAGG4, TB, 0, stream>>>(perm, row_start, row_end, src_u16, als, ald, hb, b1, fBb);

    // ---- Layer 2 ----
    gemm_att40<<<GG40, 256, 0, stream>>>(fBb, W2e, hb40, als, ald);
    dst_agg40<<<GAGG4, TB, 0, stream>>>(perm, row_start, row_end, src_u16, als, ald, hb40, b2, out);
}

// Round 17
// 187.380 us; speedup vs baseline: 2.2782x; 2.2782x over previous
//
#include <hip/hip_runtime.h>

#define NN    50000
#define ERAW  800000
#define ETOT  850000
#define NBUCK 782            // ceil(NN/64) buckets of 64 dst nodes
#define EBR   1280           // fixed edges-per-bucket region (mean 1087, sigma 33)
#define EPB_A 4096
#define NBLK_A ((ETOT + EPB_A - 1) / EPB_A)   // 208
#define NCNT  (NBUCK * 64)
#define INV_LN2 1.4426950408889634f

typedef __attribute__((ext_vector_type(8))) short bf16x8;
typedef __attribute__((ext_vector_type(4))) float f32x4;

union U16x8 { uint4 u; bf16x8 s; };
__device__ __forceinline__ bf16x8 as_bf(uint4 v) { U16x8 t; t.u = v; return t.s; }

__device__ __forceinline__ void edge_sd(const int* __restrict__ ei, int e, int& s, int& d) {
    if (e < ERAW) { s = ei[e]; d = ei[ERAW + e]; }
    else { int n = e - ERAW; s = n; d = n; }
}

__device__ __forceinline__ unsigned pack_bf16x2(float a, float b) {
    unsigned ua = __float_as_uint(a), ub = __float_as_uint(b);
    ua += 0x7fffu + ((ua >> 16) & 1u);
    ub += 0x7fffu + ((ub >> 16) & 1u);
    return (ua >> 16) | (ub & 0xffff0000u);
}
__device__ __forceinline__ float2 unpack_bf16x2(unsigned v) {
    float2 r;
    r.x = __uint_as_float(v << 16);
    r.y = __uint_as_float(v & 0xffff0000u);
    return r;
}

// ---------------- prep (blocks 0..45) + x->bf16 conversion (blocks 46..) ----------------
__global__ void prep_conv(const float* __restrict__ x,
                          const float* __restrict__ W0, const float* __restrict__ W1,
                          const float* __restrict__ W2,
                          const float* __restrict__ as0, const float* __restrict__ ad0,
                          const float* __restrict__ as1, const float* __restrict__ ad1,
                          const float* __restrict__ as2, const float* __restrict__ ad2,
                          unsigned* __restrict__ Wbp0, unsigned* __restrict__ Wbp1,
                          unsigned* __restrict__ Wadp0, unsigned* __restrict__ Wadp1,
                          float* __restrict__ W2e, int* __restrict__ cursor,
                          unsigned* __restrict__ xb) {
    if (blockIdx.x >= 46) {
        int g = (blockIdx.x - 46) * 256 + threadIdx.x;
        if (g >= NN * 32) return;
        float4 v = ((const float4*)x)[g];
        uint2 o;
        o.x = pack_bf16x2(v.x, v.y);
        o.y = pack_bf16x2(v.z, v.w);
        ((uint2*)xb)[g] = o;
        return;
    }
    int g = blockIdx.x * 256 + threadIdx.x;
    if (g < 4096) {
        // B-fragment prepack of W0/W1: col = ct*16+(l&15), k = kc*32+(l>>4)*8 ..+7
        int which = g >> 11;
        int r = g & 2047;
        int ct = r >> 8, kc = (r >> 6) & 3, l = r & 63;
        int lr = l & 15, lg = l >> 4;
        int col = ct * 16 + lr, k0 = kc * 32 + lg * 8;
        const float* W = which ? W1 : W0;
        unsigned* O = which ? Wbp1 : Wbp0;
        uint4 o;
        o.x = pack_bf16x2(W[(k0 + 0) * 128 + col], W[(k0 + 1) * 128 + col]);
        o.y = pack_bf16x2(W[(k0 + 2) * 128 + col], W[(k0 + 3) * 128 + col]);
        o.z = pack_bf16x2(W[(k0 + 4) * 128 + col], W[(k0 + 5) * 128 + col]);
        o.w = pack_bf16x2(W[(k0 + 6) * 128 + col], W[(k0 + 7) * 128 + col]);
        ((uint4*)O)[(ct * 4 + kc) * 64 + l] = o;
    } else if (g < 4608) {
        // Folded attention weights scaled by 1/ln2 (exp2 trick)
        int gg = g - 4096;
        int which = gg >> 8;
        int r = gg & 255;
        int kc = r >> 6, l = r & 63;
        int lr = l & 15, lg = l >> 4;
        const float* W = which ? W1 : W0;
        const float* av = (lr < 8) ? (which ? as1 : as0) : (which ? ad1 : ad0);
        unsigned* O = which ? Wadp1 : Wadp0;
        int h = lr & 7;
        int k0 = kc * 32 + lg * 8;
        float v[8];
        #pragma unroll
        for (int j = 0; j < 8; ++j) {
            float s = 0.f;
            #pragma unroll
            for (int c = 0; c < 16; ++c) s += W[(k0 + j) * 128 + h * 16 + c] * av[h * 16 + c];
            v[j] = s * INV_LN2;
        }
        uint4 o;
        o.x = pack_bf16x2(v[0], v[1]);
        o.y = pack_bf16x2(v[2], v[3]);
        o.z = pack_bf16x2(v[4], v[5]);
        o.w = pack_bf16x2(v[6], v[7]);
        ((uint4*)O)[kc * 64 + l] = o;
    } else if (g < 4608 + 6144) {
        // W2e[128][48]: cols 0..39 = W2, col 40 = W2@as2/ln2, col 41 = W2@ad2/ln2
        int gg = g - 4608;
        int k = gg / 48, j = gg - k * 48;
        float v = 0.f;
        if (j < 40) v = W2[k * 40 + j];
        else if (j == 40) { for (int c = 0; c < 40; ++c) v += W2[k * 40 + c] * as2[c]; v *= INV_LN2; }
        else if (j == 41) { for (int c = 0; c < 40; ++c) v += W2[k * 40 + c] * ad2[c]; v *= INV_LN2; }
        W2e[k * 48 + j] = v;
    } else if (g < 10752 + NBUCK) {
        int b = g - 10752;
        cursor[b] = b * EBR;
    }
}

// ---------------- CSR: bucket scatter into fixed regions ----------------
__global__ __launch_bounds__(256) void kA3(const int* __restrict__ ei, int* __restrict__ cursor,
                                           unsigned* __restrict__ ebkt) {
    __shared__ int lb[NBUCK];
    int t = threadIdx.x;
    for (int i = t; i < NBUCK; i += 256) lb[i] = 0;
    __syncthreads();
    int base = blockIdx.x * EPB_A;
    #pragma unroll 4
    for (int k = 0; k < EPB_A / 256; ++k) {
        int e = base + k * 256 + t;
        if (e < ETOT) {
            int s, d; edge_sd(ei, e, s, d); (void)s;
            atomicAdd(&lb[d >> 6], 1);
        }
    }
    __syncthreads();
    for (int i = t; i < NBUCK; i += 256) {
        int c = lb[i];
        lb[i] = c ? atomicAdd(&cursor[i], c) : 0;
    }
    __syncthreads();
    #pragma unroll 4
    for (int k = 0; k < EPB_A / 256; ++k) {
        int e = base + k * 256 + t;
        if (e < ETOT) {
            int s, d; edge_sd(ei, e, s, d);
            int b = d >> 6;
            int pos = atomicAdd(&lb[b], 1);
            if (pos < (b + 1) * EBR)                      // overflow clamp (P ~ 1e-6)
                ebkt[pos] = ((unsigned)d << 16) | (unsigned)s;
        }
    }
}

// per-bucket count + scan + row_start/row_end + within-region scatter
__global__ __launch_bounds__(256) void kB(const int* __restrict__ cursor,
                                          const unsigned* __restrict__ ebkt,
                                          int* __restrict__ row_start, int* __restrict__ row_end,
                                          unsigned short* __restrict__ src_u16) {
    __shared__ int lc[64];
    int b = blockIdx.x, t = threadIdx.x;
    if (t < 64) lc[t] = 0;
    __syncthreads();
    int s0 = b * EBR;
    int s1 = cursor[b]; if (s1 > s0 + EBR) s1 = s0 + EBR;
    for (int i = s0 + t; i < s1; i += 256) atomicAdd(&lc[(ebkt[i] >> 16) & 63], 1);
    __syncthreads();
    if (t < 64) {
        int v = lc[t];
        int inc = v;
        #pragma unroll
        for (int off = 1; off < 64; off <<= 1) {
            int u = __shfl_up(inc, off);
            if (t >= off) inc += u;
        }
        int st = s0 + inc - v;
        row_start[b * 64 + t] = st;
        row_end[b * 64 + t] = st + v;
        lc[t] = st;
    }
    __syncthreads();
    for (int i = s0 + t; i < s1; i += 256) {
        unsigned k = ebkt[i];
        int pos = atomicAdd(&lc[(k >> 16) & 63], 1);
        src_u16[pos] = (unsigned short)(k & 0xffffu);
    }
}

// ---------------- MFMA GEMM (layers 0/1) + fused als/ald MFMA ----------------
__global__ __launch_bounds__(256) void gemm_mfma128(
    const uint4* __restrict__ xb, const uint4* __restrict__ Wbp,
    const uint4* __restrict__ Wadp, unsigned* __restrict__ hb,
    float* __restrict__ als, float* __restrict__ ald)
{
    int t = threadIdx.x;
    int wv = t >> 6, l = t & 63;
    int lr = l & 15, lg = l >> 4;
    int n0 = blockIdx.x * 64 + wv * 16;
    int nodeA = n0 + lr; if (nodeA >= NN) nodeA = NN - 1;
    const uint4* xr = xb + (size_t)nodeA * 16;
    uint4 a0 = xr[0 * 4 + lg];
    uint4 a1 = xr[1 * 4 + lg];
    uint4 a2 = xr[2 * 4 + lg];
    uint4 a3 = xr[3 * 4 + lg];
    #pragma unroll
    for (int ct = 0; ct < 8; ++ct) {
        const uint4* bp = Wbp + (size_t)(ct * 4) * 64;
        uint4 b0 = bp[0 * 64 + l];
        uint4 b1 = bp[1 * 64 + l];
        uint4 b2 = bp[2 * 64 + l];
        uint4 b3 = bp[3 * 64 + l];
        f32x4 acc = {0.f, 0.f, 0.f, 0.f};
        acc = __builtin_amdgcn_mfma_f32_16x16x32_bf16(as_bf(a0), as_bf(b0), acc, 0, 0, 0);
        acc = __builtin_amdgcn_mfma_f32_16x16x32_bf16(as_bf(a1), as_bf(b1), acc, 0, 0, 0);
        acc = __builtin_amdgcn_mfma_f32_16x16x32_bf16(as_bf(a2), as_bf(b2), acc, 0, 0, 0);
        acc = __builtin_amdgcn_mfma_f32_16x16x32_bf16(as_bf(a3), as_bf(b3), acc, 0, 0, 0);
        #pragma unroll
        for (int j = 0; j < 4; ++j) {
            float hv = acc[j];
            float nbv = __shfl_xor(hv, 1);
            int node = n0 + lg * 4 + j;
            if ((lr & 1) == 0 && node < NN)
                hb[(size_t)node * 64 + ct * 8 + (lr >> 1)] = pack_bf16x2(hv, nbv);
        }
    }
    // fused attention coefficients (pre-scaled by 1/ln2): cols 0..7 als, 8..15 ald
    {
        uint4 b0 = Wadp[0 * 64 + l];
        uint4 b1 = Wadp[1 * 64 + l];
        uint4 b2 = Wadp[2 * 64 + l];
        uint4 b3 = Wadp[3 * 64 + l];
        f32x4 acc = {0.f, 0.f, 0.f, 0.f};
        acc = __builtin_amdgcn_mfma_f32_16x16x32_bf16(as_bf(a0), as_bf(b0), acc, 0, 0, 0);
        acc = __builtin_amdgcn_mfma_f32_16x16x32_bf16(as_bf(a1), as_bf(b1), acc, 0, 0, 0);
        acc = __builtin_amdgcn_mfma_f32_16x16x32_bf16(as_bf(a2), as_bf(b2), acc, 0, 0, 0);
        acc = __builtin_amdgcn_mfma_f32_16x16x32_bf16(as_bf(a3), as_bf(b3), acc, 0, 0, 0);
        #pragma unroll
        for (int j = 0; j < 4; ++j) {
            int node = n0 + lg * 4 + j;
            if (node < NN) {
                if (lr < 8) als[node * 8 + lr] = acc[j];
                else        ald[node * 8 + (lr - 8)] = acc[j];
            }
        }
    }
}

// ---------------- GEMM layer 2 (bf16 in, W2e with folded als/ald cols) ----------------
__global__ __launch_bounds__(256) void gemm_att40(
    const unsigned* __restrict__ fb, const float* __restrict__ W2e,
    unsigned* __restrict__ hb40, float* __restrict__ als, float* __restrict__ ald)
{
    __shared__ float ws[128 * 48];
    __shared__ unsigned xs[16 * 64];
    int t = threadIdx.x;
    int n0 = blockIdx.x * 16;
    #pragma unroll
    for (int i = 0; i < 6; ++i) ((float4*)ws)[i * 256 + t] = ((const float4*)W2e)[i * 256 + t];
    ((uint4*)xs)[t] = ((const uint4*)fb)[(size_t)n0 * 16 + t];
    __syncthreads();
    int w = t >> 6, c = t & 63;
    int cc = c < 42 ? c : 41;
    float acc[4] = {0.f, 0.f, 0.f, 0.f};
    #pragma unroll 4
    for (int kc = 0; kc < 32; ++kc) {
        float w0 = ws[(kc * 4 + 0) * 48 + cc];
        float w1 = ws[(kc * 4 + 1) * 48 + cc];
        float w2 = ws[(kc * 4 + 2) * 48 + cc];
        float w3 = ws[(kc * 4 + 3) * 48 + cc];
        #pragma unroll
        for (int i = 0; i < 4; ++i) {
            float2 f0 = unpack_bf16x2(xs[(4 * w + i) * 64 + kc * 2]);
            float2 f1 = unpack_bf16x2(xs[(4 * w + i) * 64 + kc * 2 + 1]);
            acc[i] = fmaf(f0.x, w0, acc[i]);
            acc[i] = fmaf(f0.y, w1, acc[i]);
            acc[i] = fmaf(f1.x, w2, acc[i]);
            acc[i] = fmaf(f1.y, w3, acc[i]);
        }
    }
    #pragma unroll
    for (int i = 0; i < 4; ++i) {
        int n = n0 + 4 * w + i;
        float nb = __shfl_xor(acc[i], 1);
        if ((c & 1) == 0 && c < 40) hb40[(size_t)n * 32 + (c >> 1)] = pack_bf16x2(acc[i], nb);
        if (c == 40) als[n] = acc[i];
        if (c == 41) ald[n] = acc[i];
    }
}

// ---------------- fused single-pass softmax + aggregate + finalize ----------------
// FOUR nodes per wave: 16 lanes/node; lane l covers features 8l..8l+7 (one uint4).
template<bool RELU>
__global__ void dst_agg128(const int* __restrict__ row_start, const int* __restrict__ row_end,
                           const unsigned short* __restrict__ src_u16,
                           const float* __restrict__ als, const float* __restrict__ ald,
                           const unsigned* __restrict__ hb, const float* __restrict__ bias,
                           unsigned* __restrict__ outb)
{
    int wp = (blockIdx.x * blockDim.x + threadIdx.x) >> 6;
    if (wp >= NN / 4) return;
    int lane = threadIdx.x & 63;
    int q = lane >> 4, l = lane & 15;
    int node = 4 * wp + q;
    int myh = l >> 1;
    float aldv = ald[node * 8 + myh];
    int i = row_start[node], end = row_end[node];
    float4 accA = make_float4(0.f, 0.f, 0.f, 0.f);
    float4 accB = make_float4(0.f, 0.f, 0.f, 0.f);
    float den = 0.f;
    while (__any(i + 4 <= end)) {
        if (i + 4 <= end) {
            int s0 = src_u16[i], s1 = src_u16[i + 1], s2 = src_u16[i + 2], s3 = src_u16[i + 3];
            float e0 = als[s0 * 8 + myh] + aldv;
            float e1 = als[s1 * 8 + myh] + aldv;
            float e2 = als[s2 * 8 + myh] + aldv;
            float e3 = als[s3 * 8 + myh] + aldv;
            uint4 p0 = ((const uint4*)(hb + (size_t)s0 * 64))[l];
            uint4 p1 = ((const uint4*)(hb + (size_t)s1 * 64))[l];
            uint4 p2 = ((const uint4*)(hb + (size_t)s2 * 64))[l];
            uint4 p3 = ((const uint4*)(hb + (size_t)s3 * 64))[l];
            e0 = e0 > 0.f ? e0 : 0.2f * e0;
            e1 = e1 > 0.f ? e1 : 0.2f * e1;
            e2 = e2 > 0.f ? e2 : 0.2f * e2;
            e3 = e3 > 0.f ? e3 : 0.2f * e3;
            float a0 = exp2f(e0), a1 = exp2f(e1), a2 = exp2f(e2), a3 = exp2f(e3);
            den += (a0 + a1) + (a2 + a3);
            float2 t0, t1;
            t0 = unpack_bf16x2(p0.x); t1 = unpack_bf16x2(p0.y);
            accA.x = fmaf(t0.x, a0, accA.x); accA.y = fmaf(t0.y, a0, accA.y);
            accA.z = fmaf(t1.x, a0, accA.z); accA.w = fmaf(t1.y, a0, accA.w);
            t0 = unpack_bf16x2(p0.z); t1 = unpack_bf16x2(p0.w);
            accB.x = fmaf(t0.x, a0, accB.x); accB.y = fmaf(t0.y, a0, accB.y);
            accB.z = fmaf(t1.x, a0, accB.z); accB.w = fmaf(t1.y, a0, accB.w);
            t0 = unpack_bf16x2(p1.x); t1 = unpack_bf16x2(p1.y);
            accA.x = fmaf(t0.x, a1, accA.x); accA.y = fmaf(t0.y, a1, accA.y);
            accA.z = fmaf(t1.x, a1, accA.z); accA.w = fmaf(t1.y, a1, accA.w);
            t0 = unpack_bf16x2(p1.z); t1 = unpack_bf16x2(p1.w);
            accB.x = fmaf(t0.x, a1, accB.x); accB.y = fmaf(t0.y, a1, accB.y);
            accB.z = fmaf(t1.x, a1, accB.z); accB.w = fmaf(t1.y, a1, accB.w);
            t0 = unpack_bf16x2(p2.x); t1 = unpack_bf16x2(p2.y);
            accA.x = fmaf(t0.x, a2, accA.x); accA.y = fmaf(t0.y, a2, accA.y);
            accA.z = fmaf(t1.x, a2, accA.z); accA.w = fmaf(t1.y, a2, accA.w);
            t0 = unpack_bf16x2(p2.z); t1 = unpack_bf16x2(p2.w);
            accB.x = fmaf(t0.x, a2, accB.x); accB.y = fmaf(t0.y, a2, accB.y);
            accB.z = fmaf(t1.x, a2, accB.z); accB.w = fmaf(t1.y, a2, accB.w);
            t0 = unpack_bf16x2(p3.x); t1 = unpack_bf16x2(p3.y);
            accA.x = fmaf(t0.x, a3, accA.x); accA.y = fmaf(t0.y, a3, accA.y);
            accA.z = fmaf(t1.x, a3, accA.z); accA.w = fmaf(t1.y, a3, accA.w);
            t0 = unpack_bf16x2(p3.z); t1 = unpack_bf16x2(p3.w);
            accB.x = fmaf(t0.x, a3, accB.x); accB.y = fmaf(t0.y, a3, accB.y);
            accB.z = fmaf(t1.x, a3, accB.z); accB.w = fmaf(t1.y, a3, accB.w);
            i += 4;
        }
    }
    while (__any(i < end)) {
        if (i < end) {
            int s0 = src_u16[i];
            float e0 = als[s0 * 8 + myh] + aldv;
            e0 = e0 > 0.f ? e0 : 0.2f * e0;
            float a0 = exp2f(e0);
            den += a0;
            uint4 p0 = ((const uint4*)(hb + (size_t)s0 * 64))[l];
            float2 t0 = unpack_bf16x2(p0.x), t1 = unpack_bf16x2(p0.y);
            accA.x = fmaf(t0.x, a0, accA.x); accA.y = fmaf(t0.y, a0, accA.y);
            accA.z = fmaf(t1.x, a0, accA.z); accA.w = fmaf(t1.y, a0, accA.w);
            t0 = unpack_bf16x2(p0.z); t1 = unpack_bf16x2(p0.w);
            accB.x = fmaf(t0.x, a0, accB.x); accB.y = fmaf(t0.y, a0, accB.y);
            accB.z = fmaf(t1.x, a0, accB.z); accB.w = fmaf(t1.y, a0, accB.w);
            ++i;
        }
    }
    float inv = 1.f / (den + 1e-16f);
    float4 bvA = ((const float4*)bias)[2 * l];
    float4 bvB = ((const float4*)bias)[2 * l + 1];
    float4 oA, oB;
    oA.x = accA.x * inv + bvA.x; oA.y = accA.y * inv + bvA.y;
    oA.z = accA.z * inv + bvA.z; oA.w = accA.w * inv + bvA.w;
    oB.x = accB.x * inv + bvB.x; oB.y = accB.y * inv + bvB.y;
    oB.z = accB.z * inv + bvB.z; oB.w = accB.w * inv + bvB.w;
    if (RELU) {
        oA.x = fmaxf(oA.x, 0.f); oA.y = fmaxf(oA.y, 0.f);
        oA.z = fmaxf(oA.z, 0.f); oA.w = fmaxf(oA.w, 0.f);
        oB.x = fmaxf(oB.x, 0.f); oB.y = fmaxf(oB.y, 0.f);
        oB.z = fmaxf(oB.z, 0.f); oB.w = fmaxf(oB.w, 0.f);
    }
    uint4 ob;
    ob.x = pack_bf16x2(oA.x, oA.y);
    ob.y = pack_bf16x2(oA.z, oA.w);
    ob.z = pack_bf16x2(oB.x, oB.y);
    ob.w = pack_bf16x2(oB.z, oB.w);
    ((uint4*)(outb + (size_t)node * 64))[l] = ob;
}

// H=1, C=40: FOUR nodes per wave (16 lanes each; lanes l<10 own uint2 feature pairs).
__global__ void dst_agg40(const int* __restrict__ row_start, const int* __restrict__ row_end,
                          const unsigned short* __restrict__ src_u16,
                          const float* __restrict__ als, const float* __restrict__ ald,
                          const unsigned* __restrict__ hb40, const float* __restrict__ bias,
                          float* __restrict__ out)
{
    int wp = (blockIdx.x * blockDim.x + threadIdx.x) >> 6;
    if (wp >= NN / 4) return;
    int lane = threadIdx.x & 63;
    int q = lane >> 4, l = lane & 15;
    int node = 4 * wp + q;
    float aldv = ald[node];
    int i = row_start[node], end = row_end[node];
    float4 acc = make_float4(0.f, 0.f, 0.f, 0.f);
    float den = 0.f;
    while (__any(i + 4 <= end)) {
        if (i + 4 <= end) {
            int s0 = src_u16[i], s1 = src_u16[i + 1], s2 = src_u16[i + 2], s3 = src_u16[i + 3];
            float e0 = als[s0] + aldv;
            float e1 = als[s1] + aldv;
            float e2 = als[s2] + aldv;
            float e3 = als[s3] + aldv;
            uint2 p0 = ((const uint2*)(hb40 + (size_t)s0 * 32))[l];
            uint2 p1 = ((const uint2*)(hb40 + (size_t)s1 * 32))[l];
            uint2 p2 = ((const uint2*)(hb40 + (size_t)s2 * 32))[l];
            uint2 p3 = ((const uint2*)(hb40 + (size_t)s3 * 32))[l];
            e0 = e0 > 0.f ? e0 : 0.2f * e0;
            e1 = e1 > 0.f ? e1 : 0.2f * e1;
            e2 = e2 > 0.f ? e2 : 0.2f * e2;
            e3 = e3 > 0.f ? e3 : 0.2f * e3;
            float b0 = exp2f(e0), b1 = exp2f(e1), b2 = exp2f(e2), b3 = exp2f(e3);
            den += (b0 + b1) + (b2 + b3);
            float2 u0 = unpack_bf16x2(p0.x), v0 = unpack_bf16x2(p0.y);
            float2 u1 = unpack_bf16x2(p1.x), v1 = unpack_bf16x2(p1.y);
            float2 u2 = unpack_bf16x2(p2.x), v2 = unpack_bf16x2(p2.y);
            float2 u3 = unpack_bf16x2(p3.x), v3 = unpack_bf16x2(p3.y);
            acc.x = fmaf(u0.x, b0, acc.x); acc.y = fmaf(u0.y, b0, acc.y);
            acc.z = fmaf(v0.x, b0, acc.z); acc.w = fmaf(v0.y, b0, acc.w);
            acc.x = fmaf(u1.x, b1, acc.x); acc.y = fmaf(u1.y, b1, acc.y);
            acc.z = fmaf(v1.x, b1, acc.z); acc.w = fmaf(v1.y, b1, acc.w);
            acc.x = fmaf(u2.x, b2, acc.x); acc.y = fmaf(u2.y, b2, acc.y);
            acc.z = fmaf(v2.x, b2, acc.z); acc.w = fmaf(v2.y, b2, acc.w);
            acc.x = fmaf(u3.x, b3, acc.x); acc.y = fmaf(u3.y, b3, acc.y);
            acc.z = fmaf(v3.x, b3, acc.z); acc.w = fmaf(v3.y, b3, acc.w);
            i += 4;
        }
    }
    while (__any(i < end)) {
        if (i < end) {
            int s0 = src_u16[i];
            float e0 = als[s0] + aldv;
            e0 = e0 > 0.f ? e0 : 0.2f * e0;
            float b0 = exp2f(e0);
            den += b0;
            uint2 p0 = ((const uint2*)(hb40 + (size_t)s0 * 32))[l];
            float2 u0 = unpack_bf16x2(p0.x), v0 = unpack_bf16x2(p0.y);
            acc.x = fmaf(u0.x, b0, acc.x); acc.y = fmaf(u0.y, b0, acc.y);
            acc.z = fmaf(v0.x, b0, acc.z); acc.w = fmaf(v0.y, b0, acc.w);
            ++i;
        }
    }
    if (l < 10) {
        float inv = 1.f / (den + 1e-16f);
        float4 bv = ((const float4*)bias)[l];
        float4 o;
        o.x = acc.x * inv + bv.x;
        o.y = acc.y * inv + bv.y;
        o.z = acc.z * inv + bv.z;
        o.w = acc.w * inv + bv.w;
        ((float4*)(out + (size_t)node * 40))[l] = o;
    }
}

extern "C" void kernel_launch(void* const* d_in, const int* in_sizes, int n_in,
                              void* d_out, int out_size, void* d_ws, size_t ws_size,
                              hipStream_t stream) {
    const float* x   = (const float*)d_in[0];
    const int*   ei  = (const int*)d_in[1];
    const float* W0  = (const float*)d_in[2];
    const float* as0 = (const float*)d_in[3];
    const float* ad0 = (const float*)d_in[4];
    const float* b0  = (const float*)d_in[5];
    const float* W1  = (const float*)d_in[6];
    const float* as1 = (const float*)d_in[7];
    const float* ad1 = (const float*)d_in[8];
    const float* b1  = (const float*)d_in[9];
    const float* W2  = (const float*)d_in[10];
    const float* as2 = (const float*)d_in[11];
    const float* ad2 = (const float*)d_in[12];
    const float* b2  = (const float*)d_in[13];
    float* out = (float*)d_out;

    float* ws = (float*)d_ws;
    size_t off = 0;
    unsigned* hb   = (unsigned*)(ws + off); off += (size_t)NN * 64;
    unsigned* xb   = (unsigned*)(ws + off); off += (size_t)NN * 64;
    unsigned* fAb  = (unsigned*)(ws + off); off += (size_t)NN * 64;
    unsigned* fBb  = (unsigned*)(ws + off); off += (size_t)NN * 64;
    unsigned* hb40 = (unsigned*)(ws + off); off += (size_t)NN * 32;
    float* als     = ws + off; off += (size_t)NN * 8;
    float* ald     = ws + off; off += (size_t)NN * 8;
    unsigned* Wbp0 = (unsigned*)(ws + off); off += 8192;
    unsigned* Wbp1 = (unsigned*)(ws + off); off += 8192;
    unsigned* Wadp0 = (unsigned*)(ws + off); off += 1024;
    unsigned* Wadp1 = (unsigned*)(ws + off); off += 1024;
    float* W2e     = ws + off; off += 128 * 48;
    int* ibase      = (int*)(ws + off);
    int* cursor     = ibase; ibase += NBUCK;
    int* row_start  = ibase; ibase += NCNT;
    int* row_end    = ibase; ibase += NCNT;
    unsigned* ebkt  = (unsigned*)ibase; ibase += NBUCK * EBR;
    unsigned short* src_u16 = (unsigned short*)ibase;

    const int TB = 256;

    // ---- prep (weights, folded+scaled attention weights, cursor) + x->bf16 ----
    prep_conv<<<46 + (NN * 32 + TB - 1) / TB, TB, 0, stream>>>(
        x, W0, W1, W2, as0, ad0, as1, ad1, as2, ad2,
        Wbp0, Wbp1, Wadp0, Wadp1, W2e, cursor, xb);
    // ---- CSR build (fixed-region bucket sort; shared by all 3 layers) ----
    kA3<<<NBLK_A, 256, 0, stream>>>(ei, cursor, ebkt);
    kB<<<NBUCK, 256, 0, stream>>>(cursor, ebkt, row_start, row_end, src_u16);

    const int GGM   = (NN + 63) / 64;                 // 782
    const int GG40  = NN / 16;                        // 3125
    const int GAGG4 = ((NN / 4) * 64 + TB - 1) / TB;  // 3125

    // ---- Layer 0 ----
    gemm_mfma128<<<GGM, 256, 0, stream>>>((const uint4*)xb, (const uint4*)Wbp0,
                                          (const uint4*)Wadp0, hb, als, ald);
    dst_agg128<true><<<GAGG4, TB, 0, stream>>>(row_start, row_end, src_u16, als, ald, hb, b0, fAb);

    // ---- Layer 1 ----
    gemm_mfma128<<<GGM, 256, 0, stream>>>((const uint4*)fAb, (const uint4*)Wbp1,
                                          (const uint4*)Wadp1, hb, als, ald);
    dst_agg128<true><<<GAGG4, TB, 0, stream>>>(row_start, row_end, src_u16, als, ald, hb, b1, fBb);

    // ---- Layer 2 ----
    gemm_att40<<<GG40, 256, 0, stream>>>(fBb, W2e, hb40, als, ald);
    dst_agg40<<<GAGG4, TB, 0, stream>>>(row_start, row_end, src_u16, als, ald, hb40, b2, out);
}

// Round 18
// 178.859 us; speedup vs baseline: 2.3867x; 1.0476x over previous
//
#include <hip/hip_runtime.h>

#define NN    50000
#define ERAW  800000
#define ETOT  850000
#define NBUCK 782            // ceil(NN/64) buckets of 64 dst nodes
#define EBR   1280           // fixed edges-per-bucket region (mean 1087, sigma 33)
#define EPB_A 4096
#define NBLK_A ((ETOT + EPB_A - 1) / EPB_A)   // 208
#define NCNT  (NBUCK * 64)
#define INV_LN2 1.4426950408889634f

typedef __attribute__((ext_vector_type(8))) short bf16x8;
typedef __attribute__((ext_vector_type(4))) float f32x4;

union U16x8 { uint4 u; bf16x8 s; };
__device__ __forceinline__ bf16x8 as_bf(uint4 v) { U16x8 t; t.u = v; return t.s; }

__device__ __forceinline__ void edge_sd(const int* __restrict__ ei, int e, int& s, int& d) {
    if (e < ERAW) { s = ei[e]; d = ei[ERAW + e]; }
    else { int n = e - ERAW; s = n; d = n; }
}

__device__ __forceinline__ unsigned pack_bf16x2(float a, float b) {
    unsigned ua = __float_as_uint(a), ub = __float_as_uint(b);
    ua += 0x7fffu + ((ua >> 16) & 1u);
    ub += 0x7fffu + ((ub >> 16) & 1u);
    return (ua >> 16) | (ub & 0xffff0000u);
}
__device__ __forceinline__ float2 unpack_bf16x2(unsigned v) {
    float2 r;
    r.x = __uint_as_float(v << 16);
    r.y = __uint_as_float(v & 0xffff0000u);
    return r;
}

// ---------------- prep (blocks 0..45) + x->bf16 conversion (blocks 46..) ----------------
__global__ void prep_conv(const float* __restrict__ x,
                          const float* __restrict__ W0, const float* __restrict__ W1,
                          const float* __restrict__ W2,
                          const float* __restrict__ as0, const float* __restrict__ ad0,
                          const float* __restrict__ as1, const float* __restrict__ ad1,
                          const float* __restrict__ as2, const float* __restrict__ ad2,
                          unsigned* __restrict__ Wbp0, unsigned* __restrict__ Wbp1,
                          unsigned* __restrict__ Wadp0, unsigned* __restrict__ Wadp1,
                          float* __restrict__ W2e, int* __restrict__ cursor,
                          unsigned* __restrict__ xb) {
    if (blockIdx.x >= 46) {
        int g = (blockIdx.x - 46) * 256 + threadIdx.x;
        if (g >= NN * 32) return;
        float4 v = ((const float4*)x)[g];
        uint2 o;
        o.x = pack_bf16x2(v.x, v.y);
        o.y = pack_bf16x2(v.z, v.w);
        ((uint2*)xb)[g] = o;
        return;
    }
    int g = blockIdx.x * 256 + threadIdx.x;
    if (g < 4096) {
        // B-fragment prepack of W0/W1: col = ct*16+(l&15), k = kc*32+(l>>4)*8 ..+7
        int which = g >> 11;
        int r = g & 2047;
        int ct = r >> 8, kc = (r >> 6) & 3, l = r & 63;
        int lr = l & 15, lg = l >> 4;
        int col = ct * 16 + lr, k0 = kc * 32 + lg * 8;
        const float* W = which ? W1 : W0;
        unsigned* O = which ? Wbp1 : Wbp0;
        uint4 o;
        o.x = pack_bf16x2(W[(k0 + 0) * 128 + col], W[(k0 + 1) * 128 + col]);
        o.y = pack_bf16x2(W[(k0 + 2) * 128 + col], W[(k0 + 3) * 128 + col]);
        o.z = pack_bf16x2(W[(k0 + 4) * 128 + col], W[(k0 + 5) * 128 + col]);
        o.w = pack_bf16x2(W[(k0 + 6) * 128 + col], W[(k0 + 7) * 128 + col]);
        ((uint4*)O)[(ct * 4 + kc) * 64 + l] = o;
    } else if (g < 4608) {
        // Folded attention weights scaled by 1/ln2 (exp2 trick)
        int gg = g - 4096;
        int which = gg >> 8;
        int r = gg & 255;
        int kc = r >> 6, l = r & 63;
        int lr = l & 15, lg = l >> 4;
        const float* W = which ? W1 : W0;
        const float* av = (lr < 8) ? (which ? as1 : as0) : (which ? ad1 : ad0);
        unsigned* O = which ? Wadp1 : Wadp0;
        int h = lr & 7;
        int k0 = kc * 32 + lg * 8;
        float v[8];
        #pragma unroll
        for (int j = 0; j < 8; ++j) {
            float s = 0.f;
            #pragma unroll
            for (int c = 0; c < 16; ++c) s += W[(k0 + j) * 128 + h * 16 + c] * av[h * 16 + c];
            v[j] = s * INV_LN2;
        }
        uint4 o;
        o.x = pack_bf16x2(v[0], v[1]);
        o.y = pack_bf16x2(v[2], v[3]);
        o.z = pack_bf16x2(v[4], v[5]);
        o.w = pack_bf16x2(v[6], v[7]);
        ((uint4*)O)[kc * 64 + l] = o;
    } else if (g < 4608 + 6144) {
        // W2e[128][48]: cols 0..39 = W2, col 40 = W2@as2/ln2, col 41 = W2@ad2/ln2
        int gg = g - 4608;
        int k = gg / 48, j = gg - k * 48;
        float v = 0.f;
        if (j < 40) v = W2[k * 40 + j];
        else if (j == 40) { for (int c = 0; c < 40; ++c) v += W2[k * 40 + c] * as2[c]; v *= INV_LN2; }
        else if (j == 41) { for (int c = 0; c < 40; ++c) v += W2[k * 40 + c] * ad2[c]; v *= INV_LN2; }
        W2e[k * 48 + j] = v;
    } else if (g < 10752 + NBUCK) {
        int b = g - 10752;
        cursor[b] = b * EBR;
    }
}

// ---------------- fused: CSR bucket scatter (blocks 0..207) | MFMA GEMM layer 0 ----------------
// The two roles are data-independent (both depend only on prep_conv outputs), so one
// launch overlaps the small 208-block scatter with the 782-block GEMM.
__global__ __launch_bounds__(256) void kA3_gemm0(
    const int* __restrict__ ei, int* __restrict__ cursor, unsigned* __restrict__ ebkt,
    const uint4* __restrict__ xb, const uint4* __restrict__ Wbp,
    const uint4* __restrict__ Wadp, unsigned* __restrict__ hb,
    float* __restrict__ als, float* __restrict__ ald)
{
    __shared__ int lb[NBUCK];
    int t = threadIdx.x;
    if (blockIdx.x < NBLK_A) {
        // ---- kA3 role ----
        for (int i = t; i < NBUCK; i += 256) lb[i] = 0;
        __syncthreads();
        int base = blockIdx.x * EPB_A;
        #pragma unroll 4
        for (int k = 0; k < EPB_A / 256; ++k) {
            int e = base + k * 256 + t;
            if (e < ETOT) {
                int s, d; edge_sd(ei, e, s, d); (void)s;
                atomicAdd(&lb[d >> 6], 1);
            }
        }
        __syncthreads();
        for (int i = t; i < NBUCK; i += 256) {
            int c = lb[i];
            lb[i] = c ? atomicAdd(&cursor[i], c) : 0;
        }
        __syncthreads();
        #pragma unroll 4
        for (int k = 0; k < EPB_A / 256; ++k) {
            int e = base + k * 256 + t;
            if (e < ETOT) {
                int s, d; edge_sd(ei, e, s, d);
                int b = d >> 6;
                int pos = atomicAdd(&lb[b], 1);
                if (pos < (b + 1) * EBR)                  // overflow clamp (P ~ 1e-6)
                    ebkt[pos] = ((unsigned)d << 16) | (unsigned)s;
            }
        }
        return;
    }
    // ---- gemm layer-0 role ----
    int blk = blockIdx.x - NBLK_A;
    int wv = t >> 6, l = t & 63;
    int lr = l & 15, lg = l >> 4;
    int n0 = blk * 64 + wv * 16;
    int nodeA = n0 + lr; if (nodeA >= NN) nodeA = NN - 1;
    const uint4* xr = xb + (size_t)nodeA * 16;
    uint4 a0 = xr[0 * 4 + lg];
    uint4 a1 = xr[1 * 4 + lg];
    uint4 a2 = xr[2 * 4 + lg];
    uint4 a3 = xr[3 * 4 + lg];
    #pragma unroll
    for (int ct = 0; ct < 8; ++ct) {
        const uint4* bp = Wbp + (size_t)(ct * 4) * 64;
        uint4 b0 = bp[0 * 64 + l];
        uint4 b1 = bp[1 * 64 + l];
        uint4 b2 = bp[2 * 64 + l];
        uint4 b3 = bp[3 * 64 + l];
        f32x4 acc = {0.f, 0.f, 0.f, 0.f};
        acc = __builtin_amdgcn_mfma_f32_16x16x32_bf16(as_bf(a0), as_bf(b0), acc, 0, 0, 0);
        acc = __builtin_amdgcn_mfma_f32_16x16x32_bf16(as_bf(a1), as_bf(b1), acc, 0, 0, 0);
        acc = __builtin_amdgcn_mfma_f32_16x16x32_bf16(as_bf(a2), as_bf(b2), acc, 0, 0, 0);
        acc = __builtin_amdgcn_mfma_f32_16x16x32_bf16(as_bf(a3), as_bf(b3), acc, 0, 0, 0);
        #pragma unroll
        for (int j = 0; j < 4; ++j) {
            float hv = acc[j];
            float nbv = __shfl_xor(hv, 1);
            int node = n0 + lg * 4 + j;
            if ((lr & 1) == 0 && node < NN)
                hb[(size_t)node * 64 + ct * 8 + (lr >> 1)] = pack_bf16x2(hv, nbv);
        }
    }
    {
        uint4 b0 = Wadp[0 * 64 + l];
        uint4 b1 = Wadp[1 * 64 + l];
        uint4 b2 = Wadp[2 * 64 + l];
        uint4 b3 = Wadp[3 * 64 + l];
        f32x4 acc = {0.f, 0.f, 0.f, 0.f};
        acc = __builtin_amdgcn_mfma_f32_16x16x32_bf16(as_bf(a0), as_bf(b0), acc, 0, 0, 0);
        acc = __builtin_amdgcn_mfma_f32_16x16x32_bf16(as_bf(a1), as_bf(b1), acc, 0, 0, 0);
        acc = __builtin_amdgcn_mfma_f32_16x16x32_bf16(as_bf(a2), as_bf(b2), acc, 0, 0, 0);
        acc = __builtin_amdgcn_mfma_f32_16x16x32_bf16(as_bf(a3), as_bf(b3), acc, 0, 0, 0);
        #pragma unroll
        for (int j = 0; j < 4; ++j) {
            int node = n0 + lg * 4 + j;
            if (node < NN) {
                if (lr < 8) als[node * 8 + lr] = acc[j];
                else        ald[node * 8 + (lr - 8)] = acc[j];
            }
        }
    }
}

// per-bucket count + scan + row_start/row_end + within-region scatter
__global__ __launch_bounds__(256) void kB(const int* __restrict__ cursor,
                                          const unsigned* __restrict__ ebkt,
                                          int* __restrict__ row_start, int* __restrict__ row_end,
                                          unsigned short* __restrict__ src_u16) {
    __shared__ int lc[64];
    int b = blockIdx.x, t = threadIdx.x;
    if (t < 64) lc[t] = 0;
    __syncthreads();
    int s0 = b * EBR;
    int s1 = cursor[b]; if (s1 > s0 + EBR) s1 = s0 + EBR;
    for (int i = s0 + t; i < s1; i += 256) atomicAdd(&lc[(ebkt[i] >> 16) & 63], 1);
    __syncthreads();
    if (t < 64) {
        int v = lc[t];
        int inc = v;
        #pragma unroll
        for (int off = 1; off < 64; off <<= 1) {
            int u = __shfl_up(inc, off);
            if (t >= off) inc += u;
        }
        int st = s0 + inc - v;
        row_start[b * 64 + t] = st;
        row_end[b * 64 + t] = st + v;
        lc[t] = st;
    }
    __syncthreads();
    for (int i = s0 + t; i < s1; i += 256) {
        unsigned k = ebkt[i];
        int pos = atomicAdd(&lc[(k >> 16) & 63], 1);
        src_u16[pos] = (unsigned short)(k & 0xffffu);
    }
}

// ---------------- MFMA GEMM (layer 1) + fused als/ald MFMA ----------------
__global__ __launch_bounds__(256) void gemm_mfma128(
    const uint4* __restrict__ xb, const uint4* __restrict__ Wbp,
    const uint4* __restrict__ Wadp, unsigned* __restrict__ hb,
    float* __restrict__ als, float* __restrict__ ald)
{
    int t = threadIdx.x;
    int wv = t >> 6, l = t & 63;
    int lr = l & 15, lg = l >> 4;
    int n0 = blockIdx.x * 64 + wv * 16;
    int nodeA = n0 + lr; if (nodeA >= NN) nodeA = NN - 1;
    const uint4* xr = xb + (size_t)nodeA * 16;
    uint4 a0 = xr[0 * 4 + lg];
    uint4 a1 = xr[1 * 4 + lg];
    uint4 a2 = xr[2 * 4 + lg];
    uint4 a3 = xr[3 * 4 + lg];
    #pragma unroll
    for (int ct = 0; ct < 8; ++ct) {
        const uint4* bp = Wbp + (size_t)(ct * 4) * 64;
        uint4 b0 = bp[0 * 64 + l];
        uint4 b1 = bp[1 * 64 + l];
        uint4 b2 = bp[2 * 64 + l];
        uint4 b3 = bp[3 * 64 + l];
        f32x4 acc = {0.f, 0.f, 0.f, 0.f};
        acc = __builtin_amdgcn_mfma_f32_16x16x32_bf16(as_bf(a0), as_bf(b0), acc, 0, 0, 0);
        acc = __builtin_amdgcn_mfma_f32_16x16x32_bf16(as_bf(a1), as_bf(b1), acc, 0, 0, 0);
        acc = __builtin_amdgcn_mfma_f32_16x16x32_bf16(as_bf(a2), as_bf(b2), acc, 0, 0, 0);
        acc = __builtin_amdgcn_mfma_f32_16x16x32_bf16(as_bf(a3), as_bf(b3), acc, 0, 0, 0);
        #pragma unroll
        for (int j = 0; j < 4; ++j) {
            float hv = acc[j];
            float nbv = __shfl_xor(hv, 1);
            int node = n0 + lg * 4 + j;
            if ((lr & 1) == 0 && node < NN)
                hb[(size_t)node * 64 + ct * 8 + (lr >> 1)] = pack_bf16x2(hv, nbv);
        }
    }
    // fused attention coefficients (pre-scaled by 1/ln2): cols 0..7 als, 8..15 ald
    {
        uint4 b0 = Wadp[0 * 64 + l];
        uint4 b1 = Wadp[1 * 64 + l];
        uint4 b2 = Wadp[2 * 64 + l];
        uint4 b3 = Wadp[3 * 64 + l];
        f32x4 acc = {0.f, 0.f, 0.f, 0.f};
        acc = __builtin_amdgcn_mfma_f32_16x16x32_bf16(as_bf(a0), as_bf(b0), acc, 0, 0, 0);
        acc = __builtin_amdgcn_mfma_f32_16x16x32_bf16(as_bf(a1), as_bf(b1), acc, 0, 0, 0);
        acc = __builtin_amdgcn_mfma_f32_16x16x32_bf16(as_bf(a2), as_bf(b2), acc, 0, 0, 0);
        acc = __builtin_amdgcn_mfma_f32_16x16x32_bf16(as_bf(a3), as_bf(b3), acc, 0, 0, 0);
        #pragma unroll
        for (int j = 0; j < 4; ++j) {
            int node = n0 + lg * 4 + j;
            if (node < NN) {
                if (lr < 8) als[node * 8 + lr] = acc[j];
                else        ald[node * 8 + (lr - 8)] = acc[j];
            }
        }
    }
}

// ---------------- GEMM layer 2 (bf16 in, W2e with folded als/ald cols) ----------------
__global__ __launch_bounds__(256) void gemm_att40(
    const unsigned* __restrict__ fb, const float* __restrict__ W2e,
    unsigned* __restrict__ hb40, float* __restrict__ als, float* __restrict__ ald)
{
    __shared__ float ws[128 * 48];
    __shared__ unsigned xs[16 * 64];
    int t = threadIdx.x;
    int n0 = blockIdx.x * 16;
    #pragma unroll
    for (int i = 0; i < 6; ++i) ((float4*)ws)[i * 256 + t] = ((const float4*)W2e)[i * 256 + t];
    ((uint4*)xs)[t] = ((const uint4*)fb)[(size_t)n0 * 16 + t];
    __syncthreads();
    int w = t >> 6, c = t & 63;
    int cc = c < 42 ? c : 41;
    float acc[4] = {0.f, 0.f, 0.f, 0.f};
    #pragma unroll 4
    for (int kc = 0; kc < 32; ++kc) {
        float w0 = ws[(kc * 4 + 0) * 48 + cc];
        float w1 = ws[(kc * 4 + 1) * 48 + cc];
        float w2 = ws[(kc * 4 + 2) * 48 + cc];
        float w3 = ws[(kc * 4 + 3) * 48 + cc];
        #pragma unroll
        for (int i = 0; i < 4; ++i) {
            float2 f0 = unpack_bf16x2(xs[(4 * w + i) * 64 + kc * 2]);
            float2 f1 = unpack_bf16x2(xs[(4 * w + i) * 64 + kc * 2 + 1]);
            acc[i] = fmaf(f0.x, w0, acc[i]);
            acc[i] = fmaf(f0.y, w1, acc[i]);
            acc[i] = fmaf(f1.x, w2, acc[i]);
            acc[i] = fmaf(f1.y, w3, acc[i]);
        }
    }
    #pragma unroll
    for (int i = 0; i < 4; ++i) {
        int n = n0 + 4 * w + i;
        float nb = __shfl_xor(acc[i], 1);
        if ((c & 1) == 0 && c < 40) hb40[(size_t)n * 32 + (c >> 1)] = pack_bf16x2(acc[i], nb);
        if (c == 40) als[n] = acc[i];
        if (c == 41) ald[n] = acc[i];
    }
}

// ---------------- fused single-pass softmax + aggregate + finalize ----------------
// FOUR nodes per wave: 16 lanes/node; lane l covers features 8l..8l+7 (one uint4).
template<bool RELU>
__global__ void dst_agg128(const int* __restrict__ row_start, const int* __restrict__ row_end,
                           const unsigned short* __restrict__ src_u16,
                           const float* __restrict__ als, const float* __restrict__ ald,
                           const unsigned* __restrict__ hb, const float* __restrict__ bias,
                           unsigned* __restrict__ outb)
{
    int wp = (blockIdx.x * blockDim.x + threadIdx.x) >> 6;
    if (wp >= NN / 4) return;
    int lane = threadIdx.x & 63;
    int q = lane >> 4, l = lane & 15;
    int node = 4 * wp + q;
    int myh = l >> 1;
    float aldv = ald[node * 8 + myh];
    int i = row_start[node], end = row_end[node];
    float4 accA = make_float4(0.f, 0.f, 0.f, 0.f);
    float4 accB = make_float4(0.f, 0.f, 0.f, 0.f);
    float den = 0.f;
    while (__any(i + 4 <= end)) {
        if (i + 4 <= end) {
            int s0 = src_u16[i], s1 = src_u16[i + 1], s2 = src_u16[i + 2], s3 = src_u16[i + 3];
            float e0 = als[s0 * 8 + myh] + aldv;
            float e1 = als[s1 * 8 + myh] + aldv;
            float e2 = als[s2 * 8 + myh] + aldv;
            float e3 = als[s3 * 8 + myh] + aldv;
            uint4 p0 = ((const uint4*)(hb + (size_t)s0 * 64))[l];
            uint4 p1 = ((const uint4*)(hb + (size_t)s1 * 64))[l];
            uint4 p2 = ((const uint4*)(hb + (size_t)s2 * 64))[l];
            uint4 p3 = ((const uint4*)(hb + (size_t)s3 * 64))[l];
            e0 = e0 > 0.f ? e0 : 0.2f * e0;
            e1 = e1 > 0.f ? e1 : 0.2f * e1;
            e2 = e2 > 0.f ? e2 : 0.2f * e2;
            e3 = e3 > 0.f ? e3 : 0.2f * e3;
            float a0 = exp2f(e0), a1 = exp2f(e1), a2 = exp2f(e2), a3 = exp2f(e3);
            den += (a0 + a1) + (a2 + a3);
            float2 t0, t1;
            t0 = unpack_bf16x2(p0.x); t1 = unpack_bf16x2(p0.y);
            accA.x = fmaf(t0.x, a0, accA.x); accA.y = fmaf(t0.y, a0, accA.y);
            accA.z = fmaf(t1.x, a0, accA.z); accA.w = fmaf(t1.y, a0, accA.w);
            t0 = unpack_bf16x2(p0.z); t1 = unpack_bf16x2(p0.w);
            accB.x = fmaf(t0.x, a0, accB.x); accB.y = fmaf(t0.y, a0, accB.y);
            accB.z = fmaf(t1.x, a0, accB.z); accB.w = fmaf(t1.y, a0, accB.w);
            t0 = unpack_bf16x2(p1.x); t1 = unpack_bf16x2(p1.y);
            accA.x = fmaf(t0.x, a1, accA.x); accA.y = fmaf(t0.y, a1, accA.y);
            accA.z = fmaf(t1.x, a1, accA.z); accA.w = fmaf(t1.y, a1, accA.w);
            t0 = unpack_bf16x2(p1.z); t1 = unpack_bf16x2(p1.w);
            accB.x = fmaf(t0.x, a1, accB.x); accB.y = fmaf(t0.y, a1, accB.y);
            accB.z = fmaf(t1.x, a1, accB.z); accB.w = fmaf(t1.y, a1, accB.w);
            t0 = unpack_bf16x2(p2.x); t1 = unpack_bf16x2(p2.y);
            accA.x = fmaf(t0.x, a2, accA.x); accA.y = fmaf(t0.y, a2, accA.y);
            accA.z = fmaf(t1.x, a2, accA.z); accA.w = fmaf(t1.y, a2, accA.w);
            t0 = unpack_bf16x2(p2.z); t1 = unpack_bf16x2(p2.w);
            accB.x = fmaf(t0.x, a2, accB.x); accB.y = fmaf(t0.y, a2, accB.y);
            accB.z = fmaf(t1.x, a2, accB.z); accB.w = fmaf(t1.y, a2, accB.w);
            t0 = unpack_bf16x2(p3.x); t1 = unpack_bf16x2(p3.y);
            accA.x = fmaf(t0.x, a3, accA.x); accA.y = fmaf(t0.y, a3, accA.y);
            accA.z = fmaf(t1.x, a3, accA.z); accA.w = fmaf(t1.y, a3, accA.w);
            t0 = unpack_bf16x2(p3.z); t1 = unpack_bf16x2(p3.w);
            accB.x = fmaf(t0.x, a3, accB.x); accB.y = fmaf(t0.y, a3, accB.y);
            accB.z = fmaf(t1.x, a3, accB.z); accB.w = fmaf(t1.y, a3, accB.w);
            i += 4;
        }
    }
    while (__any(i < end)) {
        if (i < end) {
            int s0 = src_u16[i];
            float e0 = als[s0 * 8 + myh] + aldv;
            e0 = e0 > 0.f ? e0 : 0.2f * e0;
            float a0 = exp2f(e0);
            den += a0;
            uint4 p0 = ((const uint4*)(hb + (size_t)s0 * 64))[l];
            float2 t0 = unpack_bf16x2(p0.x), t1 = unpack_bf16x2(p0.y);
            accA.x = fmaf(t0.x, a0, accA.x); accA.y = fmaf(t0.y, a0, accA.y);
            accA.z = fmaf(t1.x, a0, accA.z); accA.w = fmaf(t1.y, a0, accA.w);
            t0 = unpack_bf16x2(p0.z); t1 = unpack_bf16x2(p0.w);
            accB.x = fmaf(t0.x, a0, accB.x); accB.y = fmaf(t0.y, a0, accB.y);
            accB.z = fmaf(t1.x, a0, accB.z); accB.w = fmaf(t1.y, a0, accB.w);
            ++i;
        }
    }
    float inv = 1.f / (den + 1e-16f);
    float4 bvA = ((const float4*)bias)[2 * l];
    float4 bvB = ((const float4*)bias)[2 * l + 1];
    float4 oA, oB;
    oA.x = accA.x * inv + bvA.x; oA.y = accA.y * inv + bvA.y;
    oA.z = accA.z * inv + bvA.z; oA.w = accA.w * inv + bvA.w;
    oB.x = accB.x * inv + bvB.x; oB.y = accB.y * inv + bvB.y;
    oB.z = accB.z * inv + bvB.z; oB.w = accB.w * inv + bvB.w;
    if (RELU) {
        oA.x = fmaxf(oA.x, 0.f); oA.y = fmaxf(oA.y, 0.f);
        oA.z = fmaxf(oA.z, 0.f); oA.w = fmaxf(oA.w, 0.f);
        oB.x = fmaxf(oB.x, 0.f); oB.y = fmaxf(oB.y, 0.f);
        oB.z = fmaxf(oB.z, 0.f); oB.w = fmaxf(oB.w, 0.f);
    }
    uint4 ob;
    ob.x = pack_bf16x2(oA.x, oA.y);
    ob.y = pack_bf16x2(oA.z, oA.w);
    ob.z = pack_bf16x2(oB.x, oB.y);
    ob.w = pack_bf16x2(oB.z, oB.w);
    ((uint4*)(outb + (size_t)node * 64))[l] = ob;
}

// H=1, C=40: FOUR nodes per wave (16 lanes each; lanes l<10 own uint2 feature pairs).
__global__ void dst_agg40(const int* __restrict__ row_start, const int* __restrict__ row_end,
                          const unsigned short* __restrict__ src_u16,
                          const float* __restrict__ als, const float* __restrict__ ald,
                          const unsigned* __restrict__ hb40, const float* __restrict__ bias,
                          float* __restrict__ out)
{
    int wp = (blockIdx.x * blockDim.x + threadIdx.x) >> 6;
    if (wp >= NN / 4) return;
    int lane = threadIdx.x & 63;
    int q = lane >> 4, l = lane & 15;
    int node = 4 * wp + q;
    float aldv = ald[node];
    int i = row_start[node], end = row_end[node];
    float4 acc = make_float4(0.f, 0.f, 0.f, 0.f);
    float den = 0.f;
    while (__any(i + 4 <= end)) {
        if (i + 4 <= end) {
            int s0 = src_u16[i], s1 = src_u16[i + 1], s2 = src_u16[i + 2], s3 = src_u16[i + 3];
            float e0 = als[s0] + aldv;
            float e1 = als[s1] + aldv;
            float e2 = als[s2] + aldv;
            float e3 = als[s3] + aldv;
            uint2 p0 = ((const uint2*)(hb40 + (size_t)s0 * 32))[l];
            uint2 p1 = ((const uint2*)(hb40 + (size_t)s1 * 32))[l];
            uint2 p2 = ((const uint2*)(hb40 + (size_t)s2 * 32))[l];
            uint2 p3 = ((const uint2*)(hb40 + (size_t)s3 * 32))[l];
            e0 = e0 > 0.f ? e0 : 0.2f * e0;
            e1 = e1 > 0.f ? e1 : 0.2f * e1;
            e2 = e2 > 0.f ? e2 : 0.2f * e2;
            e3 = e3 > 0.f ? e3 : 0.2f * e3;
            float b0 = exp2f(e0), b1 = exp2f(e1), b2 = exp2f(e2), b3 = exp2f(e3);
            den += (b0 + b1) + (b2 + b3);
            float2 u0 = unpack_bf16x2(p0.x), v0 = unpack_bf16x2(p0.y);
            float2 u1 = unpack_bf16x2(p1.x), v1 = unpack_bf16x2(p1.y);
            float2 u2 = unpack_bf16x2(p2.x), v2 = unpack_bf16x2(p2.y);
            float2 u3 = unpack_bf16x2(p3.x), v3 = unpack_bf16x2(p3.y);
            acc.x = fmaf(u0.x, b0, acc.x); acc.y = fmaf(u0.y, b0, acc.y);
            acc.z = fmaf(v0.x, b0, acc.z); acc.w = fmaf(v0.y, b0, acc.w);
            acc.x = fmaf(u1.x, b1, acc.x); acc.y = fmaf(u1.y, b1, acc.y);
            acc.z = fmaf(v1.x, b1, acc.z); acc.w = fmaf(v1.y, b1, acc.w);
            acc.x = fmaf(u2.x, b2, acc.x); acc.y = fmaf(u2.y, b2, acc.y);
            acc.z = fmaf(v2.x, b2, acc.z); acc.w = fmaf(v2.y, b2, acc.w);
            acc.x = fmaf(u3.x, b3, acc.x); acc.y = fmaf(u3.y, b3, acc.y);
            acc.z = fmaf(v3.x, b3, acc.z); acc.w = fmaf(v3.y, b3, acc.w);
            i += 4;
        }
    }
    while (__any(i < end)) {
        if (i < end) {
            int s0 = src_u16[i];
            float e0 = als[s0] + aldv;
            e0 = e0 > 0.f ? e0 : 0.2f * e0;
            float b0 = exp2f(e0);
            den += b0;
            uint2 p0 = ((const uint2*)(hb40 + (size_t)s0 * 32))[l];
            float2 u0 = unpack_bf16x2(p0.x), v0 = unpack_bf16x2(p0.y);
            acc.x = fmaf(u0.x, b0, acc.x); acc.y = fmaf(u0.y, b0, acc.y);
            acc.z = fmaf(v0.x, b0, acc.z); acc.w = fmaf(v0.y, b0, acc.w);
            ++i;
        }
    }
    if (l < 10) {
        float inv = 1.f / (den + 1e-16f);
        float4 bv = ((const float4*)bias)[l];
        float4 o;
        o.x = acc.x * inv + bv.x;
        o.y = acc.y * inv + bv.y;
        o.z = acc.z * inv + bv.z;
        o.w = acc.w * inv + bv.w;
        ((float4*)(out + (size_t)node * 40))[l] = o;
    }
}

extern "C" void kernel_launch(void* const* d_in, const int* in_sizes, int n_in,
                              void* d_out, int out_size, void* d_ws, size_t ws_size,
                              hipStream_t stream) {
    const float* x   = (const float*)d_in[0];
    const int*   ei  = (const int*)d_in[1];
    const float* W0  = (const float*)d_in[2];
    const float* as0 = (const float*)d_in[3];
    const float* ad0 = (const float*)d_in[4];
    const float* b0  = (const float*)d_in[5];
    const float* W1  = (const float*)d_in[6];
    const float* as1 = (const float*)d_in[7];
    const float* ad1 = (const float*)d_in[8];
    const float* b1  = (const float*)d_in[9];
    const float* W2  = (const float*)d_in[10];
    const float* as2 = (const float*)d_in[11];
    const float* ad2 = (const float*)d_in[12];
    const float* b2  = (const float*)d_in[13];
    float* out = (float*)d_out;

    float* ws = (float*)d_ws;
    size_t off = 0;
    unsigned* hb   = (unsigned*)(ws + off); off += (size_t)NN * 64;
    unsigned* xb   = (unsigned*)(ws + off); off += (size_t)NN * 64;
    unsigned* fAb  = (unsigned*)(ws + off); off += (size_t)NN * 64;
    unsigned* fBb  = (unsigned*)(ws + off); off += (size_t)NN * 64;
    unsigned* hb40 = (unsigned*)(ws + off); off += (size_t)NN * 32;
    float* als     = ws + off; off += (size_t)NN * 8;
    float* ald     = ws + off; off += (size_t)NN * 8;
    unsigned* Wbp0 = (unsigned*)(ws + off); off += 8192;
    unsigned* Wbp1 = (unsigned*)(ws + off); off += 8192;
    unsigned* Wadp0 = (unsigned*)(ws + off); off += 1024;
    unsigned* Wadp1 = (unsigned*)(ws + off); off += 1024;
    float* W2e     = ws + off; off += 128 * 48;
    int* ibase      = (int*)(ws + off);
    int* cursor     = ibase; ibase += NBUCK;
    int* row_start  = ibase; ibase += NCNT;
    int* row_end    = ibase; ibase += NCNT;
    unsigned* ebkt  = (unsigned*)ibase; ibase += NBUCK * EBR;
    unsigned short* src_u16 = (unsigned short*)ibase;

    const int TB = 256;

    // ---- prep (weights, folded+scaled attention weights, cursor) + x->bf16 ----
    prep_conv<<<46 + (NN * 32 + TB - 1) / TB, TB, 0, stream>>>(
        x, W0, W1, W2, as0, ad0, as1, ad1, as2, ad2,
        Wbp0, Wbp1, Wadp0, Wadp1, W2e, cursor, xb);

    const int GGM   = (NN + 63) / 64;                 // 782
    const int GG40  = NN / 16;                        // 3125
    const int GAGG4 = ((NN / 4) * 64 + TB - 1) / TB;  // 3125

    // ---- fused: CSR bucket scatter | layer-0 GEMM (independent roles) ----
    kA3_gemm0<<<NBLK_A + GGM, 256, 0, stream>>>(ei, cursor, ebkt,
                                                (const uint4*)xb, (const uint4*)Wbp0,
                                                (const uint4*)Wadp0, hb, als, ald);
    // ---- CSR finish (bucket-local sort) ----
    kB<<<NBUCK, 256, 0, stream>>>(cursor, ebkt, row_start, row_end, src_u16);

    // ---- Layer 0 aggregate ----
    dst_agg128<true><<<GAGG4, TB, 0, stream>>>(row_start, row_end, src_u16, als, ald, hb, b0, fAb);

    // ---- Layer 1 ----
    gemm_mfma128<<<GGM, 256, 0, stream>>>((const uint4*)fAb, (const uint4*)Wbp1,
                                          (const uint4*)Wadp1, hb, als, ald);
    dst_agg128<true><<<GAGG4, TB, 0, stream>>>(row_start, row_end, src_u16, als, ald, hb, b1, fBb);

    // ---- Layer 2 ----
    gemm_att40<<<GG40, 256, 0, stream>>>(fBb, W2e, hb40, als, ald);
    dst_agg40<<<GAGG4, TB, 0, stream>>>(row_start, row_end, src_u16, als, ald, hb40, b2, out);
}